// Round 10
// baseline (333.481 us; speedup 1.0000x reference)
//
#include <hip/hip_runtime.h>

typedef short bf16x8 __attribute__((ext_vector_type(8)));
typedef float f32x4 __attribute__((ext_vector_type(4)));
typedef unsigned short u16;

#define NB 8
#define NS 1024
#define NE 768
#define NH 12
#define ND 64
#define QSCALE 0.18033688011112042f   // 0.125 * log2(e): scores land in log2 domain

__device__ __forceinline__ u16 f2bf(float f){
  unsigned u = __float_as_uint(f);
  u += 0x7fffu + ((u >> 16) & 1u);
  return (u16)(u >> 16);
}

// pack two fp32 -> two bf16 (round-half-up) in one u32 via v_perm
__device__ __forceinline__ unsigned pack2bf(float a, float b){
  unsigned ua = __float_as_uint(a) + 0x8000u;
  unsigned ub = __float_as_uint(b) + 0x8000u;
  return __builtin_amdgcn_perm(ub, ua, 0x07060302u);
}

#define EXP2(x) __builtin_amdgcn_exp2f(x)

// ---------------- fused fp32 -> bf16 convert (x, Wqkv, out_w in one launch) ----------------
// R9 lesson: converting x once is cheaper than re-reading fp32 x 18x in the GEMM.
__global__ void cvt3_kernel(const float* __restrict__ s0, const float* __restrict__ s1,
                            const float* __restrict__ s2,
                            u16* __restrict__ d0, u16* __restrict__ d1, u16* __restrict__ d2){
  const int n0 = 1572864, n1 = 442368, n2 = 147456;   // float4 counts
  int i = blockIdx.x * 256 + threadIdx.x;
  const float* s; u16* d; int j;
  if (i < n0){ s = s0; d = d0; j = i; }
  else if (i < n0 + n1){ s = s1; d = d1; j = i - n0; }
  else { s = s2; d = d2; j = i - n0 - n1; }
  float4 v = ((const float4*)s)[j];
  ushort4 o;
  o.x = f2bf(v.x); o.y = f2bf(v.y); o.z = f2bf(v.z); o.w = f2bf(v.w);
  ((ushort4*)d)[j] = o;
}

// ---------------- lengths from prefix mask (dtype auto-detect) ----------------
__global__ void lengths_kernel(const unsigned int* __restrict__ mi, int* __restrict__ lens){
  __shared__ int isByte;
  int tid = threadIdx.x;
  int any = 0;
  for (int i = tid; i < 2048; i += 512) any |= (mi[i] > 1u) ? 1 : 0;
  if (tid == 0) isByte = 0;
  __syncthreads();
  if (any) atomicOr(&isByte, 1);
  __syncthreads();
  int byteMode = isByte;
  int b = tid >> 6, lane = tid & 63;
  int cnt = 0;
  if (byteMode){
    const unsigned char* p = (const unsigned char*)mi;
    for (int j = 0; j < 16; ++j) cnt += p[b*NS + j*64 + lane] ? 1 : 0;
  } else {
    for (int j = 0; j < 16; ++j) cnt += mi[b*NS + j*64 + lane] ? 1 : 0;
  }
  for (int o = 1; o < 64; o <<= 1) cnt += __shfl_xor(cnt, o, 64);
  if (lane == 0) lens[b] = cnt;
}

// ================= GEMMs: R7 structure + attn-style XOR-swizzled LDS =================
// LDS per matrix: [kc][128 rows][32 u16] (64 B rows). Chunk swizzle: write chunk
// ((srow>>1)+c)&3, read chunk ((l16>>1)+quad)&3 — both sides 2-way max (free, m136).
// Replaces 144B padded rows whose staging writes were 4-way conflicted (7.08M cyc, ~20%).
// (256,3): measured VGPR 104-112 < 170 cap -> no spill (R3: cap 128 DID spill).
// 1-D grid, xcd = bid&7: 8 m-blocks per XCD -> x-tiles L2-local across n-blocks.

// ---------------- QKV projection GEMM: [8192,768] x [2304,768]^T, BK=64 ----------------
__global__ __launch_bounds__(256, 3) void gemm_qkv(
    const u16* __restrict__ A, const u16* __restrict__ Bw,
    const float* __restrict__ bias,
    u16* __restrict__ qb, u16* __restrict__ kb, u16* __restrict__ vb)
{
  __shared__ __align__(16) u16 smA[2][128*32];
  __shared__ __align__(16) u16 smB[2][128*32];
  const int tid = threadIdx.x;
  const int lane = tid & 63;
  const int wave = tid >> 6;
  const int quad = lane >> 4, l16 = lane & 15;
  const int wm = wave >> 1, wn = wave & 1;
  const int xcd = blockIdx.x & 7;
  const int g   = blockIdx.x >> 3;          // 0..143
  const int nb  = g % 18;
  const int mb  = xcd*8 + g/18;             // 0..63
  const int m0 = mb * 128;
  const int n0 = nb * 128;
  const int which = nb / 6;                 // 0=q, 1=k, 2=v (uniform per block)

  const int srow = tid >> 2;
  const int c4 = tid & 3;
  const int soff = c4 * 16;
  const int wc = (((srow >> 1) + c4) & 3) * 16;        // swizzled LDS chunk (write)
  const int pc8 = (((l16 >> 1) + quad) & 3) * 8;       // swizzled chunk (read, u16)

  const char* gA = (const char*)A + ((size_t)(m0 + srow)*NE)*2 + soff;
  const char* gB = (const char*)Bw + ((size_t)(n0 + srow)*NE)*2 + soff;
  uint4 a00 = *(const uint4*)(gA);
  uint4 a01 = *(const uint4*)(gA + 64);
  uint4 a10 = *(const uint4*)(gA + (size_t)64*NE*2);
  uint4 a11 = *(const uint4*)(gA + (size_t)64*NE*2 + 64);
  uint4 b00 = *(const uint4*)(gB);
  uint4 b01 = *(const uint4*)(gB + 64);
  uint4 b10 = *(const uint4*)(gB + (size_t)64*NE*2);
  uint4 b11 = *(const uint4*)(gB + (size_t)64*NE*2 + 64);

  char* lA0 = (char*)&smA[0][0] + srow*64 + wc;
  char* lA1 = (char*)&smA[1][0] + srow*64 + wc;
  char* lB0 = (char*)&smB[0][0] + srow*64 + wc;
  char* lB1 = (char*)&smB[1][0] + srow*64 + wc;

  f32x4 acc[4][4] = {};

  for (int kt = 0; kt < NE; kt += 64){
    __syncthreads();                 // prior readers done (vmcnt for prefetch drains here)
    *(uint4*)lA0 = a00; *(uint4*)lA1 = a01;
    *(uint4*)(lA0 + 64*64) = a10; *(uint4*)(lA1 + 64*64) = a11;
    *(uint4*)lB0 = b00; *(uint4*)lB1 = b01;
    *(uint4*)(lB0 + 64*64) = b10; *(uint4*)(lB1 + 64*64) = b11;
    __syncthreads();
    if (kt + 64 < NE){               // prefetch next K-tile (hidden behind 32 MFMA)
      const char* nA = gA + (kt + 64)*2;
      const char* nB = gB + (kt + 64)*2;
      a00 = *(const uint4*)nA; a01 = *(const uint4*)(nA + 64);
      a10 = *(const uint4*)(nA + (size_t)64*NE*2); a11 = *(const uint4*)(nA + (size_t)64*NE*2 + 64);
      b00 = *(const uint4*)nB; b01 = *(const uint4*)(nB + 64);
      b10 = *(const uint4*)(nB + (size_t)64*NE*2); b11 = *(const uint4*)(nB + (size_t)64*NE*2 + 64);
    }
    #pragma unroll
    for (int kc = 0; kc < 2; ++kc){
      bf16x8 av[4], bv[4];
      #pragma unroll
      for (int i = 0; i < 4; ++i){
        av[i] = *(const bf16x8*)&smA[kc][(wm*64 + i*16 + l16)*32 + pc8];
        bv[i] = *(const bf16x8*)&smB[kc][(wn*64 + i*16 + l16)*32 + pc8];
      }
      if (which < 2){
        #pragma unroll
        for (int mi = 0; mi < 4; ++mi)
          #pragma unroll
          for (int ni = 0; ni < 4; ++ni)
            acc[mi][ni] = __builtin_amdgcn_mfma_f32_16x16x32_bf16(bv[ni], av[mi], acc[mi][ni], 0, 0, 0);
      } else {
        #pragma unroll
        for (int mi = 0; mi < 4; ++mi)
          #pragma unroll
          for (int ni = 0; ni < 4; ++ni)
            acc[mi][ni] = __builtin_amdgcn_mfma_f32_16x16x32_bf16(av[mi], bv[ni], acc[mi][ni], 0, 0, 0);
      }
    }
  }

  if (which < 2){
    // swapped: m on l16, n on (quad,r) -> 4 consecutive d per lane
    u16* dst = (which == 0) ? qb : kb;
    const float sc = (which == 0) ? QSCALE : 1.0f;
    #pragma unroll
    for (int ni = 0; ni < 4; ++ni){
      int gcol0 = n0 + wn*64 + ni*16 + quad*4;
      int rem = gcol0 - which*NE;
      int hh = rem >> 6, dd0 = rem & 63;
      float4 b4 = *(const float4*)&bias[gcol0];
      #pragma unroll
      for (int mi = 0; mi < 4; ++mi){
        int grow = m0 + wm*64 + mi*16 + l16;
        int bb = grow >> 10, ss = grow & 1023;
        int bh = bb*NH + hh;
        float v0 = (acc[mi][ni][0] + b4.x)*sc, v1 = (acc[mi][ni][1] + b4.y)*sc;
        float v2 = (acc[mi][ni][2] + b4.z)*sc, v3 = (acc[mi][ni][3] + b4.w)*sc;
        uint2 pr; pr.x = pack2bf(v0, v1); pr.y = pack2bf(v2, v3);
        *(uint2*)&dst[((size_t)bh*NS + ss)*ND + dd0] = pr;
      }
    }
  } else {
    // normal: n on l16, m(=s) on (quad,r) -> 4 consecutive s per lane in (b,h,d,s)
    #pragma unroll
    for (int ni = 0; ni < 4; ++ni){
      int gcol = n0 + wn*64 + ni*16 + l16;
      int rem = gcol - 2*NE;
      int hh = rem >> 6, dd = rem & 63;
      float bval = bias[gcol];
      #pragma unroll
      for (int mi = 0; mi < 4; ++mi){
        int grow0 = m0 + wm*64 + mi*16 + quad*4;
        int bb = grow0 >> 10, ss0 = grow0 & 1023;
        int bh = bb*NH + hh;
        float v0 = acc[mi][ni][0] + bval, v1 = acc[mi][ni][1] + bval;
        float v2 = acc[mi][ni][2] + bval, v3 = acc[mi][ni][3] + bval;
        uint2 pr; pr.x = pack2bf(v0, v1); pr.y = pack2bf(v2, v3);
        *(uint2*)&vb[((size_t)bh*ND + dd)*NS + ss0] = pr;
      }
    }
  }
}

// ---------------- flash attention (R7 version, unchanged) ----------------
__global__ __launch_bounds__(256, 4) void attn_kernel(
    const u16* __restrict__ qb, const u16* __restrict__ kb,
    const u16* __restrict__ vb, const int* __restrict__ lens,
    u16* __restrict__ ctx)
{
  __shared__ __align__(16) u16 smK[2][2][64*32];   // [buf][kc]
  __shared__ __align__(16) u16 smV[2][2][64*32];
  __shared__ __align__(16) u16 smP[4][16*64];      // 128 B/row

  const int tid = threadIdx.x, lane = tid & 63, wave = tid >> 6;
  const int quad = lane >> 4, l16 = lane & 15;
  const int bh = blockIdx.x;
  const int b = bh / NH;
  const int h = bh - b*NH;
  const int q0 = blockIdx.y * 64;
  const int len = lens[b];

  // dead q-tile: all rows masked -> ctx rows are zero; skip the whole K-loop
  if (q0 >= len){
    int q = q0 + wave*16 + l16;
    size_t base = (size_t)(b*NS + q)*NE + h*ND;
    uint2 z; z.x = 0u; z.y = 0u;
    #pragma unroll
    for (int di = 0; di < 4; ++di)
      *(uint2*)&ctx[base + di*16 + quad*4] = z;
    return;
  }

  const int r0 = tid >> 2;
  const int ch = (tid & 3) * 16;                         // global 16B chunk
  const int wc = ((((r0 >> 1) + (tid & 3)) & 3) * 16);   // swizzled LDS chunk (write)
  const int pc8 = (((l16 >> 1) + quad) & 3) * 8;         // swizzled chunk (read, u16 units)

  // Q fragments straight from global (loop-invariant per wave)
  bf16x8 qf[2];
  {
    const char* gq = (const char*)qb + (size_t)(bh*NS + q0 + wave*16 + l16)*128 + quad*16;
    qf[0] = *(const bf16x8*)(gq);
    qf[1] = *(const bf16x8*)(gq + 64);
  }

  // K/V stage tile 0 into buf 0
  const char* gk = (const char*)kb + ((size_t)bh*NS + r0)*128 + ch;
  const char* gv = (const char*)vb + ((size_t)(bh*ND + r0))*(NS*2) + ch;
  {
    uint4 kp0 = *(const uint4*)(gk);
    uint4 kp1 = *(const uint4*)(gk + 64);
    uint4 vp0 = *(const uint4*)(gv);
    uint4 vp1 = *(const uint4*)(gv + 64);
    *(uint4*)((char*)smK[0][0] + r0*64 + wc) = kp0;
    *(uint4*)((char*)smK[0][1] + r0*64 + wc) = kp1;
    *(uint4*)((char*)smV[0][0] + r0*64 + wc) = vp0;
    *(uint4*)((char*)smV[0][1] + r0*64 + wc) = vp1;
  }
  __syncthreads();

  float m_i = -1e30f, l_i = 0.f;
  f32x4 accO[4] = {};
  const int ntiles = (len + 63) >> 6;
  char* pRow = (char*)&smP[wave][0] + l16*128;

  uint4 kp0, kp1, vp0, vp1;
  for (int t = 0; t < ntiles; ++t){
    const int buf = t & 1;
    if (t + 1 < ntiles){                   // issue prefetch t+1 (consumed after compute)
      const char* nk = gk + (size_t)(t+1)*8192;
      const char* nv = gv + (size_t)(t+1)*128;
      kp0 = *(const uint4*)(nk); kp1 = *(const uint4*)(nk + 64);
      vp0 = *(const uint4*)(nv); vp1 = *(const uint4*)(nv + 64);
    }

    // S^T = K_tile . Q^T  (per wave: 64 keys x 16 q-rows)
    f32x4 accS[4] = {};
    #pragma unroll
    for (int kc = 0; kc < 2; ++kc){
      #pragma unroll
      for (int ni = 0; ni < 4; ++ni){
        bf16x8 ak = *(const bf16x8*)&smK[buf][kc][(ni*16 + l16)*32 + pc8];
        accS[ni] = __builtin_amdgcn_mfma_f32_16x16x32_bf16(ak, qf[kc], accS[ni], 0, 0, 0);
      }
    }

    // online softmax: lane owns q-row (l16); keys = key0 + ni*16 + quad*4 + r
    int key0 = t*64;
    float mx = -3e38f;
    if (key0 + 64 <= len){                 // full tile: no masking (wave-uniform)
      #pragma unroll
      for (int ni = 0; ni < 4; ++ni)
        #pragma unroll
        for (int r = 0; r < 4; ++r) mx = fmaxf(mx, accS[ni][r]);
    } else {
      #pragma unroll
      for (int ni = 0; ni < 4; ++ni)
        #pragma unroll
        for (int r = 0; r < 4; ++r){
          int key = key0 + ni*16 + quad*4 + r;
          float x = (key < len) ? accS[ni][r] : -1e30f;
          accS[ni][r] = x;
          mx = fmaxf(mx, x);
        }
    }
    mx = fmaxf(mx, __shfl_xor(mx, 16, 64));
    mx = fmaxf(mx, __shfl_xor(mx, 32, 64));
    float mnew = fmaxf(m_i, mx);
    float alpha = EXP2(m_i - mnew);
    float sum = 0.f;
    #pragma unroll
    for (int ni = 0; ni < 4; ++ni){
      float p0 = EXP2(accS[ni][0] - mnew);
      float p1 = EXP2(accS[ni][1] - mnew);
      float p2 = EXP2(accS[ni][2] - mnew);
      float p3 = EXP2(accS[ni][3] - mnew);
      sum += (p0 + p1) + (p2 + p3);
      int cc = ni*2 + (quad >> 1);
      uint2 pr; pr.x = pack2bf(p0, p1); pr.y = pack2bf(p2, p3);
      *(uint2*)(pRow + (((cc + l16) & 7) * 16) + (quad & 1)*8) = pr;
    }
    sum += __shfl_xor(sum, 16, 64);
    sum += __shfl_xor(sum, 32, 64);
    l_i = l_i * alpha + sum;
    m_i = mnew;
    #pragma unroll
    for (int di = 0; di < 4; ++di) accO[di] *= alpha;
    asm volatile("s_waitcnt lgkmcnt(0)" ::: "memory");

    // O^T += V^T_tile . P^T
    #pragma unroll
    for (int kc = 0; kc < 2; ++kc){
      bf16x8 bp = *(const bf16x8*)(pRow + ((((kc*4 + quad) + l16) & 7) * 16));
      #pragma unroll
      for (int di = 0; di < 4; ++di){
        bf16x8 av = *(const bf16x8*)&smV[buf][kc][(di*16 + l16)*32 + pc8];
        accO[di] = __builtin_amdgcn_mfma_f32_16x16x32_bf16(av, bp, accO[di], 0, 0, 0);
      }
    }

    if (t + 1 < ntiles){                   // stage t+1 into other buf; ONE barrier per tile
      const int nbuf = 1 - buf;
      *(uint4*)((char*)smK[nbuf][0] + r0*64 + wc) = kp0;
      *(uint4*)((char*)smK[nbuf][1] + r0*64 + wc) = kp1;
      *(uint4*)((char*)smV[nbuf][0] + r0*64 + wc) = vp0;
      *(uint4*)((char*)smV[nbuf][1] + r0*64 + wc) = vp1;
      __syncthreads();
    }
  }

  // epilogue: lane owns q-row; d = di*16 + quad*4 + r (4 consecutive -> b64 store)
  int q = q0 + wave*16 + l16;
  float inv = (q < len) ? (1.0f / l_i) : 0.f;
  size_t base = (size_t)(b*NS + q)*NE + h*ND;
  #pragma unroll
  for (int di = 0; di < 4; ++di){
    float v0 = accO[di][0]*inv, v1 = accO[di][1]*inv;
    float v2 = accO[di][2]*inv, v3 = accO[di][3]*inv;
    uint2 pr; pr.x = pack2bf(v0, v1); pr.y = pack2bf(v2, v3);
    *(uint2*)&ctx[base + di*16 + quad*4] = pr;
  }
}

// ---------------- output projection GEMM: [8192,768] x [768,768]^T -> fp32, BK=64 ----------------
__global__ __launch_bounds__(256, 3) void gemm_out(
    const u16* __restrict__ A, const u16* __restrict__ Bw,
    const float* __restrict__ bias, float* __restrict__ out)
{
  __shared__ __align__(16) u16 smA[2][128*32];
  __shared__ __align__(16) u16 smB[2][128*32];
  const int tid = threadIdx.x;
  const int lane = tid & 63;
  const int wave = tid >> 6;
  const int quad = lane >> 4, l16 = lane & 15;
  const int wm = wave >> 1, wn = wave & 1;
  const int xcd = blockIdx.x & 7;
  const int g   = blockIdx.x >> 3;          // 0..47
  const int nb  = g % 6;
  const int mb  = xcd*8 + g/6;              // 0..63
  const int m0 = mb * 128;
  const int n0 = nb * 128;

  const int srow = tid >> 2;
  const int c4 = tid & 3;
  const int soff = c4 * 16;
  const int wc = (((srow >> 1) + c4) & 3) * 16;
  const int pc8 = (((l16 >> 1) + quad) & 3) * 8;

  const char* gA = (const char*)A + ((size_t)(m0 + srow)*NE)*2 + soff;
  const char* gB = (const char*)Bw + ((size_t)(n0 + srow)*NE)*2 + soff;
  uint4 a00 = *(const uint4*)(gA);
  uint4 a01 = *(const uint4*)(gA + 64);
  uint4 a10 = *(const uint4*)(gA + (size_t)64*NE*2);
  uint4 a11 = *(const uint4*)(gA + (size_t)64*NE*2 + 64);
  uint4 b00 = *(const uint4*)(gB);
  uint4 b01 = *(const uint4*)(gB + 64);
  uint4 b10 = *(const uint4*)(gB + (size_t)64*NE*2);
  uint4 b11 = *(const uint4*)(gB + (size_t)64*NE*2 + 64);

  char* lA0 = (char*)&smA[0][0] + srow*64 + wc;
  char* lA1 = (char*)&smA[1][0] + srow*64 + wc;
  char* lB0 = (char*)&smB[0][0] + srow*64 + wc;
  char* lB1 = (char*)&smB[1][0] + srow*64 + wc;

  f32x4 acc[4][4] = {};

  for (int kt = 0; kt < NE; kt += 64){
    __syncthreads();
    *(uint4*)lA0 = a00; *(uint4*)lA1 = a01;
    *(uint4*)(lA0 + 64*64) = a10; *(uint4*)(lA1 + 64*64) = a11;
    *(uint4*)lB0 = b00; *(uint4*)lB1 = b01;
    *(uint4*)(lB0 + 64*64) = b10; *(uint4*)(lB1 + 64*64) = b11;
    __syncthreads();
    if (kt + 64 < NE){
      const char* nA = gA + (kt + 64)*2;
      const char* nB = gB + (kt + 64)*2;
      a00 = *(const uint4*)nA; a01 = *(const uint4*)(nA + 64);
      a10 = *(const uint4*)(nA + (size_t)64*NE*2); a11 = *(const uint4*)(nA + (size_t)64*NE*2 + 64);
      b00 = *(const uint4*)nB; b01 = *(const uint4*)(nB + 64);
      b10 = *(const uint4*)(nB + (size_t)64*NE*2); b11 = *(const uint4*)(nB + (size_t)64*NE*2 + 64);
    }
    #pragma unroll
    for (int kc = 0; kc < 2; ++kc){
      bf16x8 av[4], bv[4];
      #pragma unroll
      for (int i = 0; i < 4; ++i){
        av[i] = *(const bf16x8*)&smA[kc][(wm*64 + i*16 + l16)*32 + pc8];
        bv[i] = *(const bf16x8*)&smB[kc][(wn*64 + i*16 + l16)*32 + pc8];
      }
      #pragma unroll
      for (int mi = 0; mi < 4; ++mi)
        #pragma unroll
        for (int ni = 0; ni < 4; ++ni)
          acc[mi][ni] = __builtin_amdgcn_mfma_f32_16x16x32_bf16(bv[ni], av[mi], acc[mi][ni], 0, 0, 0);
    }
  }

  #pragma unroll
  for (int ni = 0; ni < 4; ++ni){
    int gcol0 = n0 + wn*64 + ni*16 + quad*4;
    float4 b4 = *(const float4*)&bias[gcol0];
    #pragma unroll
    for (int mi = 0; mi < 4; ++mi){
      int grow = m0 + wm*64 + mi*16 + l16;
      float4 o;
      o.x = acc[mi][ni][0] + b4.x; o.y = acc[mi][ni][1] + b4.y;
      o.z = acc[mi][ni][2] + b4.z; o.w = acc[mi][ni][3] + b4.w;
      *(float4*)&out[(size_t)grow*NE + gcol0] = o;
    }
  }
}

extern "C" void kernel_launch(void* const* d_in, const int* in_sizes, int n_in,
                              void* d_out, int out_size, void* d_ws, size_t ws_size,
                              hipStream_t stream)
{
  const float* x    = (const float*)d_in[0];
  const void*  mask = d_in[1];
  const float* wqkv = (const float*)d_in[2];
  const float* bqkv = (const float*)d_in[3];
  const float* wout = (const float*)d_in[4];
  const float* bout = (const float*)d_in[5];

  char* ws = (char*)d_ws;
  u16* xb    = (u16*)(ws + 0);
  u16* wqkvb = (u16*)(ws + 12582912);
  u16* woutb = (u16*)(ws + 16121856);
  u16* qbuf  = (u16*)(ws + 17301504);
  u16* kbuf  = (u16*)(ws + 29884416);
  u16* vbuf  = (u16*)(ws + 42467328);
  u16* ctxb  = (u16*)(ws + 55050240);
  int* lens  = (int*)(ws + 67633152);

  cvt3_kernel<<<8448, 256, 0, stream>>>(x, wqkv, wout, xb, wqkvb, woutb);
  lengths_kernel<<<1, 512, 0, stream>>>((const unsigned int*)mask, lens);
  gemm_qkv<<<1152, 256, 0, stream>>>(xb, wqkvb, bqkv, qbuf, kbuf, vbuf);
  attn_kernel<<<dim3(96, 16), 256, 0, stream>>>(qbuf, kbuf, vbuf, lens, ctxb);
  gemm_out<<<384, 256, 0, stream>>>(ctxb, woutb, bout, (float*)d_out);
}

// Round 11
// 193.526 us; speedup vs baseline: 1.7232x; 1.7232x over previous
//
#include <hip/hip_runtime.h>

typedef short bf16x8 __attribute__((ext_vector_type(8)));
typedef float f32x4 __attribute__((ext_vector_type(4)));
typedef unsigned short u16;

#define NB 8
#define NS 1024
#define NE 768
#define NH 12
#define ND 64
#define QSCALE 0.18033688011112042f   // 0.125 * log2(e): scores land in log2 domain

__device__ __forceinline__ u16 f2bf(float f){
  unsigned u = __float_as_uint(f);
  u += 0x7fffu + ((u >> 16) & 1u);
  return (u16)(u >> 16);
}

// pack two fp32 -> two bf16 (round-half-up) in one u32 via v_perm
__device__ __forceinline__ unsigned pack2bf(float a, float b){
  unsigned ua = __float_as_uint(a) + 0x8000u;
  unsigned ub = __float_as_uint(b) + 0x8000u;
  return __builtin_amdgcn_perm(ub, ua, 0x07060302u);
}

#define EXP2(x) __builtin_amdgcn_exp2f(x)

// ---------------- fused fp32 -> bf16 convert (x, Wqkv, out_w in one launch) ----------------
// R9 lesson: converting x once is cheaper than re-reading fp32 x 18x in the GEMM.
__global__ void cvt3_kernel(const float* __restrict__ s0, const float* __restrict__ s1,
                            const float* __restrict__ s2,
                            u16* __restrict__ d0, u16* __restrict__ d1, u16* __restrict__ d2){
  const int n0 = 1572864, n1 = 442368, n2 = 147456;   // float4 counts
  int i = blockIdx.x * 256 + threadIdx.x;
  const float* s; u16* d; int j;
  if (i < n0){ s = s0; d = d0; j = i; }
  else if (i < n0 + n1){ s = s1; d = d1; j = i - n0; }
  else { s = s2; d = d2; j = i - n0 - n1; }
  float4 v = ((const float4*)s)[j];
  ushort4 o;
  o.x = f2bf(v.x); o.y = f2bf(v.y); o.z = f2bf(v.z); o.w = f2bf(v.w);
  ((ushort4*)d)[j] = o;
}

// ---------------- lengths from prefix mask (dtype auto-detect) ----------------
__global__ void lengths_kernel(const unsigned int* __restrict__ mi, int* __restrict__ lens){
  __shared__ int isByte;
  int tid = threadIdx.x;
  int any = 0;
  for (int i = tid; i < 2048; i += 512) any |= (mi[i] > 1u) ? 1 : 0;
  if (tid == 0) isByte = 0;
  __syncthreads();
  if (any) atomicOr(&isByte, 1);
  __syncthreads();
  int byteMode = isByte;
  int b = tid >> 6, lane = tid & 63;
  int cnt = 0;
  if (byteMode){
    const unsigned char* p = (const unsigned char*)mi;
    for (int j = 0; j < 16; ++j) cnt += p[b*NS + j*64 + lane] ? 1 : 0;
  } else {
    for (int j = 0; j < 16; ++j) cnt += mi[b*NS + j*64 + lane] ? 1 : 0;
  }
  for (int o = 1; o < 64; o <<= 1) cnt += __shfl_xor(cnt, o, 64);
  if (lane == 0) lens[b] = cnt;
}

// ================= GEMMs: R7 structure + XOR-swizzled LDS (R10, conflicts=0) =================
// LDS per matrix: [kc][128 rows][32 u16] (64 B rows). Chunk swizzle: write chunk
// ((srow>>1)+c)&3, read chunk ((l16>>1)+quad)&3 — measured SQ_LDS_BANK_CONFLICT = 0 (R10).
// (256,2) REQUIRED: with 64-AGPR acc, (256,3)'s arch/AGPR split pins arch VGPRs at ~84 and
// spills the 32-reg staging set -> 521 MB scratch writes (R10; same signature in R8).
// Spill tell: VGPR_Count ~84 + WRITE_SIZE inflation.
// 1-D grid, xcd = bid&7: 8 m-blocks per XCD -> x-tiles L2-local across n-blocks.

// ---------------- QKV projection GEMM: [8192,768] x [2304,768]^T, BK=64 ----------------
__global__ __launch_bounds__(256, 2) void gemm_qkv(
    const u16* __restrict__ A, const u16* __restrict__ Bw,
    const float* __restrict__ bias,
    u16* __restrict__ qb, u16* __restrict__ kb, u16* __restrict__ vb)
{
  __shared__ __align__(16) u16 smA[2][128*32];
  __shared__ __align__(16) u16 smB[2][128*32];
  const int tid = threadIdx.x;
  const int lane = tid & 63;
  const int wave = tid >> 6;
  const int quad = lane >> 4, l16 = lane & 15;
  const int wm = wave >> 1, wn = wave & 1;
  const int xcd = blockIdx.x & 7;
  const int g   = blockIdx.x >> 3;          // 0..143
  const int nb  = g % 18;
  const int mb  = xcd*8 + g/18;             // 0..63
  const int m0 = mb * 128;
  const int n0 = nb * 128;
  const int which = nb / 6;                 // 0=q, 1=k, 2=v (uniform per block)

  const int srow = tid >> 2;
  const int c4 = tid & 3;
  const int soff = c4 * 16;
  const int wc = (((srow >> 1) + c4) & 3) * 16;        // swizzled LDS chunk (write)
  const int pc8 = (((l16 >> 1) + quad) & 3) * 8;       // swizzled chunk (read, u16)

  const char* gA = (const char*)A + ((size_t)(m0 + srow)*NE)*2 + soff;
  const char* gB = (const char*)Bw + ((size_t)(n0 + srow)*NE)*2 + soff;
  uint4 a00 = *(const uint4*)(gA);
  uint4 a01 = *(const uint4*)(gA + 64);
  uint4 a10 = *(const uint4*)(gA + (size_t)64*NE*2);
  uint4 a11 = *(const uint4*)(gA + (size_t)64*NE*2 + 64);
  uint4 b00 = *(const uint4*)(gB);
  uint4 b01 = *(const uint4*)(gB + 64);
  uint4 b10 = *(const uint4*)(gB + (size_t)64*NE*2);
  uint4 b11 = *(const uint4*)(gB + (size_t)64*NE*2 + 64);

  char* lA0 = (char*)&smA[0][0] + srow*64 + wc;
  char* lA1 = (char*)&smA[1][0] + srow*64 + wc;
  char* lB0 = (char*)&smB[0][0] + srow*64 + wc;
  char* lB1 = (char*)&smB[1][0] + srow*64 + wc;

  f32x4 acc[4][4] = {};

  for (int kt = 0; kt < NE; kt += 64){
    __syncthreads();                 // prior readers done (vmcnt for prefetch drains here)
    *(uint4*)lA0 = a00; *(uint4*)lA1 = a01;
    *(uint4*)(lA0 + 64*64) = a10; *(uint4*)(lA1 + 64*64) = a11;
    *(uint4*)lB0 = b00; *(uint4*)lB1 = b01;
    *(uint4*)(lB0 + 64*64) = b10; *(uint4*)(lB1 + 64*64) = b11;
    __syncthreads();
    if (kt + 64 < NE){               // prefetch next K-tile (hidden behind 32 MFMA)
      const char* nA = gA + (kt + 64)*2;
      const char* nB = gB + (kt + 64)*2;
      a00 = *(const uint4*)nA; a01 = *(const uint4*)(nA + 64);
      a10 = *(const uint4*)(nA + (size_t)64*NE*2); a11 = *(const uint4*)(nA + (size_t)64*NE*2 + 64);
      b00 = *(const uint4*)nB; b01 = *(const uint4*)(nB + 64);
      b10 = *(const uint4*)(nB + (size_t)64*NE*2); b11 = *(const uint4*)(nB + (size_t)64*NE*2 + 64);
    }
    #pragma unroll
    for (int kc = 0; kc < 2; ++kc){
      bf16x8 av[4], bv[4];
      #pragma unroll
      for (int i = 0; i < 4; ++i){
        av[i] = *(const bf16x8*)&smA[kc][(wm*64 + i*16 + l16)*32 + pc8];
        bv[i] = *(const bf16x8*)&smB[kc][(wn*64 + i*16 + l16)*32 + pc8];
      }
      if (which < 2){
        #pragma unroll
        for (int mi = 0; mi < 4; ++mi)
          #pragma unroll
          for (int ni = 0; ni < 4; ++ni)
            acc[mi][ni] = __builtin_amdgcn_mfma_f32_16x16x32_bf16(bv[ni], av[mi], acc[mi][ni], 0, 0, 0);
      } else {
        #pragma unroll
        for (int mi = 0; mi < 4; ++mi)
          #pragma unroll
          for (int ni = 0; ni < 4; ++ni)
            acc[mi][ni] = __builtin_amdgcn_mfma_f32_16x16x32_bf16(av[mi], bv[ni], acc[mi][ni], 0, 0, 0);
      }
    }
  }

  if (which < 2){
    // swapped: m on l16, n on (quad,r) -> 4 consecutive d per lane
    u16* dst = (which == 0) ? qb : kb;
    const float sc = (which == 0) ? QSCALE : 1.0f;
    #pragma unroll
    for (int ni = 0; ni < 4; ++ni){
      int gcol0 = n0 + wn*64 + ni*16 + quad*4;
      int rem = gcol0 - which*NE;
      int hh = rem >> 6, dd0 = rem & 63;
      float4 b4 = *(const float4*)&bias[gcol0];
      #pragma unroll
      for (int mi = 0; mi < 4; ++mi){
        int grow = m0 + wm*64 + mi*16 + l16;
        int bb = grow >> 10, ss = grow & 1023;
        int bh = bb*NH + hh;
        float v0 = (acc[mi][ni][0] + b4.x)*sc, v1 = (acc[mi][ni][1] + b4.y)*sc;
        float v2 = (acc[mi][ni][2] + b4.z)*sc, v3 = (acc[mi][ni][3] + b4.w)*sc;
        uint2 pr; pr.x = pack2bf(v0, v1); pr.y = pack2bf(v2, v3);
        *(uint2*)&dst[((size_t)bh*NS + ss)*ND + dd0] = pr;
      }
    }
  } else {
    // normal: n on l16, m(=s) on (quad,r) -> 4 consecutive s per lane in (b,h,d,s)
    #pragma unroll
    for (int ni = 0; ni < 4; ++ni){
      int gcol = n0 + wn*64 + ni*16 + l16;
      int rem = gcol - 2*NE;
      int hh = rem >> 6, dd = rem & 63;
      float bval = bias[gcol];
      #pragma unroll
      for (int mi = 0; mi < 4; ++mi){
        int grow0 = m0 + wm*64 + mi*16 + quad*4;
        int bb = grow0 >> 10, ss0 = grow0 & 1023;
        int bh = bb*NH + hh;
        float v0 = acc[mi][ni][0] + bval, v1 = acc[mi][ni][1] + bval;
        float v2 = acc[mi][ni][2] + bval, v3 = acc[mi][ni][3] + bval;
        uint2 pr; pr.x = pack2bf(v0, v1); pr.y = pack2bf(v2, v3);
        *(uint2*)&vb[((size_t)bh*ND + dd)*NS + ss0] = pr;
      }
    }
  }
}

// ---------------- flash attention (R7 version, unchanged) ----------------
__global__ __launch_bounds__(256, 4) void attn_kernel(
    const u16* __restrict__ qb, const u16* __restrict__ kb,
    const u16* __restrict__ vb, const int* __restrict__ lens,
    u16* __restrict__ ctx)
{
  __shared__ __align__(16) u16 smK[2][2][64*32];   // [buf][kc]
  __shared__ __align__(16) u16 smV[2][2][64*32];
  __shared__ __align__(16) u16 smP[4][16*64];      // 128 B/row

  const int tid = threadIdx.x, lane = tid & 63, wave = tid >> 6;
  const int quad = lane >> 4, l16 = lane & 15;
  const int bh = blockIdx.x;
  const int b = bh / NH;
  const int h = bh - b*NH;
  const int q0 = blockIdx.y * 64;
  const int len = lens[b];

  // dead q-tile: all rows masked -> ctx rows are zero; skip the whole K-loop
  if (q0 >= len){
    int q = q0 + wave*16 + l16;
    size_t base = (size_t)(b*NS + q)*NE + h*ND;
    uint2 z; z.x = 0u; z.y = 0u;
    #pragma unroll
    for (int di = 0; di < 4; ++di)
      *(uint2*)&ctx[base + di*16 + quad*4] = z;
    return;
  }

  const int r0 = tid >> 2;
  const int ch = (tid & 3) * 16;                         // global 16B chunk
  const int wc = ((((r0 >> 1) + (tid & 3)) & 3) * 16);   // swizzled LDS chunk (write)
  const int pc8 = (((l16 >> 1) + quad) & 3) * 8;         // swizzled chunk (read, u16 units)

  // Q fragments straight from global (loop-invariant per wave)
  bf16x8 qf[2];
  {
    const char* gq = (const char*)qb + (size_t)(bh*NS + q0 + wave*16 + l16)*128 + quad*16;
    qf[0] = *(const bf16x8*)(gq);
    qf[1] = *(const bf16x8*)(gq + 64);
  }

  // K/V stage tile 0 into buf 0
  const char* gk = (const char*)kb + ((size_t)bh*NS + r0)*128 + ch;
  const char* gv = (const char*)vb + ((size_t)(bh*ND + r0))*(NS*2) + ch;
  {
    uint4 kp0 = *(const uint4*)(gk);
    uint4 kp1 = *(const uint4*)(gk + 64);
    uint4 vp0 = *(const uint4*)(gv);
    uint4 vp1 = *(const uint4*)(gv + 64);
    *(uint4*)((char*)smK[0][0] + r0*64 + wc) = kp0;
    *(uint4*)((char*)smK[0][1] + r0*64 + wc) = kp1;
    *(uint4*)((char*)smV[0][0] + r0*64 + wc) = vp0;
    *(uint4*)((char*)smV[0][1] + r0*64 + wc) = vp1;
  }
  __syncthreads();

  float m_i = -1e30f, l_i = 0.f;
  f32x4 accO[4] = {};
  const int ntiles = (len + 63) >> 6;
  char* pRow = (char*)&smP[wave][0] + l16*128;

  uint4 kp0, kp1, vp0, vp1;
  for (int t = 0; t < ntiles; ++t){
    const int buf = t & 1;
    if (t + 1 < ntiles){                   // issue prefetch t+1 (consumed after compute)
      const char* nk = gk + (size_t)(t+1)*8192;
      const char* nv = gv + (size_t)(t+1)*128;
      kp0 = *(const uint4*)(nk); kp1 = *(const uint4*)(nk + 64);
      vp0 = *(const uint4*)(nv); vp1 = *(const uint4*)(nv + 64);
    }

    // S^T = K_tile . Q^T  (per wave: 64 keys x 16 q-rows)
    f32x4 accS[4] = {};
    #pragma unroll
    for (int kc = 0; kc < 2; ++kc){
      #pragma unroll
      for (int ni = 0; ni < 4; ++ni){
        bf16x8 ak = *(const bf16x8*)&smK[buf][kc][(ni*16 + l16)*32 + pc8];
        accS[ni] = __builtin_amdgcn_mfma_f32_16x16x32_bf16(ak, qf[kc], accS[ni], 0, 0, 0);
      }
    }

    // online softmax: lane owns q-row (l16); keys = key0 + ni*16 + quad*4 + r
    int key0 = t*64;
    float mx = -3e38f;
    if (key0 + 64 <= len){                 // full tile: no masking (wave-uniform)
      #pragma unroll
      for (int ni = 0; ni < 4; ++ni)
        #pragma unroll
        for (int r = 0; r < 4; ++r) mx = fmaxf(mx, accS[ni][r]);
    } else {
      #pragma unroll
      for (int ni = 0; ni < 4; ++ni)
        #pragma unroll
        for (int r = 0; r < 4; ++r){
          int key = key0 + ni*16 + quad*4 + r;
          float x = (key < len) ? accS[ni][r] : -1e30f;
          accS[ni][r] = x;
          mx = fmaxf(mx, x);
        }
    }
    mx = fmaxf(mx, __shfl_xor(mx, 16, 64));
    mx = fmaxf(mx, __shfl_xor(mx, 32, 64));
    float mnew = fmaxf(m_i, mx);
    float alpha = EXP2(m_i - mnew);
    float sum = 0.f;
    #pragma unroll
    for (int ni = 0; ni < 4; ++ni){
      float p0 = EXP2(accS[ni][0] - mnew);
      float p1 = EXP2(accS[ni][1] - mnew);
      float p2 = EXP2(accS[ni][2] - mnew);
      float p3 = EXP2(accS[ni][3] - mnew);
      sum += (p0 + p1) + (p2 + p3);
      int cc = ni*2 + (quad >> 1);
      uint2 pr; pr.x = pack2bf(p0, p1); pr.y = pack2bf(p2, p3);
      *(uint2*)(pRow + (((cc + l16) & 7) * 16) + (quad & 1)*8) = pr;
    }
    sum += __shfl_xor(sum, 16, 64);
    sum += __shfl_xor(sum, 32, 64);
    l_i = l_i * alpha + sum;
    m_i = mnew;
    #pragma unroll
    for (int di = 0; di < 4; ++di) accO[di] *= alpha;
    asm volatile("s_waitcnt lgkmcnt(0)" ::: "memory");

    // O^T += V^T_tile . P^T
    #pragma unroll
    for (int kc = 0; kc < 2; ++kc){
      bf16x8 bp = *(const bf16x8*)(pRow + ((((kc*4 + quad) + l16) & 7) * 16));
      #pragma unroll
      for (int di = 0; di < 4; ++di){
        bf16x8 av = *(const bf16x8*)&smV[buf][kc][(di*16 + l16)*32 + pc8];
        accO[di] = __builtin_amdgcn_mfma_f32_16x16x32_bf16(av, bp, accO[di], 0, 0, 0);
      }
    }

    if (t + 1 < ntiles){                   // stage t+1 into other buf; ONE barrier per tile
      const int nbuf = 1 - buf;
      *(uint4*)((char*)smK[nbuf][0] + r0*64 + wc) = kp0;
      *(uint4*)((char*)smK[nbuf][1] + r0*64 + wc) = kp1;
      *(uint4*)((char*)smV[nbuf][0] + r0*64 + wc) = vp0;
      *(uint4*)((char*)smV[nbuf][1] + r0*64 + wc) = vp1;
      __syncthreads();
    }
  }

  // epilogue: lane owns q-row; d = di*16 + quad*4 + r (4 consecutive -> b64 store)
  int q = q0 + wave*16 + l16;
  float inv = (q < len) ? (1.0f / l_i) : 0.f;
  size_t base = (size_t)(b*NS + q)*NE + h*ND;
  #pragma unroll
  for (int di = 0; di < 4; ++di){
    float v0 = accO[di][0]*inv, v1 = accO[di][1]*inv;
    float v2 = accO[di][2]*inv, v3 = accO[di][3]*inv;
    uint2 pr; pr.x = pack2bf(v0, v1); pr.y = pack2bf(v2, v3);
    *(uint2*)&ctx[base + di*16 + quad*4] = pr;
  }
}

// ---------------- output projection GEMM: [8192,768] x [768,768]^T -> fp32, BK=64 ----------------
__global__ __launch_bounds__(256, 2) void gemm_out(
    const u16* __restrict__ A, const u16* __restrict__ Bw,
    const float* __restrict__ bias, float* __restrict__ out)
{
  __shared__ __align__(16) u16 smA[2][128*32];
  __shared__ __align__(16) u16 smB[2][128*32];
  const int tid = threadIdx.x;
  const int lane = tid & 63;
  const int wave = tid >> 6;
  const int quad = lane >> 4, l16 = lane & 15;
  const int wm = wave >> 1, wn = wave & 1;
  const int xcd = blockIdx.x & 7;
  const int g   = blockIdx.x >> 3;          // 0..47
  const int nb  = g % 6;
  const int mb  = xcd*8 + g/6;              // 0..63
  const int m0 = mb * 128;
  const int n0 = nb * 128;

  const int srow = tid >> 2;
  const int c4 = tid & 3;
  const int soff = c4 * 16;
  const int wc = (((srow >> 1) + c4) & 3) * 16;
  const int pc8 = (((l16 >> 1) + quad) & 3) * 8;

  const char* gA = (const char*)A + ((size_t)(m0 + srow)*NE)*2 + soff;
  const char* gB = (const char*)Bw + ((size_t)(n0 + srow)*NE)*2 + soff;
  uint4 a00 = *(const uint4*)(gA);
  uint4 a01 = *(const uint4*)(gA + 64);
  uint4 a10 = *(const uint4*)(gA + (size_t)64*NE*2);
  uint4 a11 = *(const uint4*)(gA + (size_t)64*NE*2 + 64);
  uint4 b00 = *(const uint4*)(gB);
  uint4 b01 = *(const uint4*)(gB + 64);
  uint4 b10 = *(const uint4*)(gB + (size_t)64*NE*2);
  uint4 b11 = *(const uint4*)(gB + (size_t)64*NE*2 + 64);

  char* lA0 = (char*)&smA[0][0] + srow*64 + wc;
  char* lA1 = (char*)&smA[1][0] + srow*64 + wc;
  char* lB0 = (char*)&smB[0][0] + srow*64 + wc;
  char* lB1 = (char*)&smB[1][0] + srow*64 + wc;

  f32x4 acc[4][4] = {};

  for (int kt = 0; kt < NE; kt += 64){
    __syncthreads();
    *(uint4*)lA0 = a00; *(uint4*)lA1 = a01;
    *(uint4*)(lA0 + 64*64) = a10; *(uint4*)(lA1 + 64*64) = a11;
    *(uint4*)lB0 = b00; *(uint4*)lB1 = b01;
    *(uint4*)(lB0 + 64*64) = b10; *(uint4*)(lB1 + 64*64) = b11;
    __syncthreads();
    if (kt + 64 < NE){
      const char* nA = gA + (kt + 64)*2;
      const char* nB = gB + (kt + 64)*2;
      a00 = *(const uint4*)nA; a01 = *(const uint4*)(nA + 64);
      a10 = *(const uint4*)(nA + (size_t)64*NE*2); a11 = *(const uint4*)(nA + (size_t)64*NE*2 + 64);
      b00 = *(const uint4*)nB; b01 = *(const uint4*)(nB + 64);
      b10 = *(const uint4*)(nB + (size_t)64*NE*2); b11 = *(const uint4*)(nB + (size_t)64*NE*2 + 64);
    }
    #pragma unroll
    for (int kc = 0; kc < 2; ++kc){
      bf16x8 av[4], bv[4];
      #pragma unroll
      for (int i = 0; i < 4; ++i){
        av[i] = *(const bf16x8*)&smA[kc][(wm*64 + i*16 + l16)*32 + pc8];
        bv[i] = *(const bf16x8*)&smB[kc][(wn*64 + i*16 + l16)*32 + pc8];
      }
      #pragma unroll
      for (int mi = 0; mi < 4; ++mi)
        #pragma unroll
        for (int ni = 0; ni < 4; ++ni)
          acc[mi][ni] = __builtin_amdgcn_mfma_f32_16x16x32_bf16(bv[ni], av[mi], acc[mi][ni], 0, 0, 0);
    }
  }

  #pragma unroll
  for (int ni = 0; ni < 4; ++ni){
    int gcol0 = n0 + wn*64 + ni*16 + quad*4;
    float4 b4 = *(const float4*)&bias[gcol0];
    #pragma unroll
    for (int mi = 0; mi < 4; ++mi){
      int grow = m0 + wm*64 + mi*16 + l16;
      float4 o;
      o.x = acc[mi][ni][0] + b4.x; o.y = acc[mi][ni][1] + b4.y;
      o.z = acc[mi][ni][2] + b4.z; o.w = acc[mi][ni][3] + b4.w;
      *(float4*)&out[(size_t)grow*NE + gcol0] = o;
    }
  }
}

extern "C" void kernel_launch(void* const* d_in, const int* in_sizes, int n_in,
                              void* d_out, int out_size, void* d_ws, size_t ws_size,
                              hipStream_t stream)
{
  const float* x    = (const float*)d_in[0];
  const void*  mask = d_in[1];
  const float* wqkv = (const float*)d_in[2];
  const float* bqkv = (const float*)d_in[3];
  const float* wout = (const float*)d_in[4];
  const float* bout = (const float*)d_in[5];

  char* ws = (char*)d_ws;
  u16* xb    = (u16*)(ws + 0);
  u16* wqkvb = (u16*)(ws + 12582912);
  u16* woutb = (u16*)(ws + 16121856);
  u16* qbuf  = (u16*)(ws + 17301504);
  u16* kbuf  = (u16*)(ws + 29884416);
  u16* vbuf  = (u16*)(ws + 42467328);
  u16* ctxb  = (u16*)(ws + 55050240);
  int* lens  = (int*)(ws + 67633152);

  cvt3_kernel<<<8448, 256, 0, stream>>>(x, wqkv, wout, xb, wqkvb, woutb);
  lengths_kernel<<<1, 512, 0, stream>>>((const unsigned int*)mask, lens);
  gemm_qkv<<<1152, 256, 0, stream>>>(xb, wqkvb, bqkv, qbuf, kbuf, vbuf);
  attn_kernel<<<dim3(96, 16), 256, 0, stream>>>(qbuf, kbuf, vbuf, lens, ctxb);
  gemm_out<<<384, 256, 0, stream>>>(ctxb, woutb, bout, (float*)d_out);
}